// Round 12
// baseline (217.462 us; speedup 1.0000x reference)
//
#include <hip/hip_runtime.h>
#include <hip/hip_bf16.h>

#define N_NODES 50000
#define N_EDGES 500000
#define D_IN    128
#define D_K     384
#define D_OUT   128
#define BN_EPS  1e-5f
#define N_TASK  (2 * N_NODES)   // recv tasks then send tasks
#define CAP     64              // bucket capacity (max degree ~30 for Poisson(10))
#define NBX     ((N_NODES + 255) / 256)    // 196 gemm x-blocks (256 nodes each)
#define PSTRIDE 200                        // padded partial stride (>= NBX)

typedef __bf16 bf16x8 __attribute__((ext_vector_type(8)));
typedef __bf16 bf16x4 __attribute__((ext_vector_type(4)));
typedef __bf16 bf16x2 __attribute__((ext_vector_type(2)));
typedef float  f32x4  __attribute__((ext_vector_type(4)));
typedef float  f32x2  __attribute__((ext_vector_type(2)));

// ---- workspace layout (bytes) ----
#define OFF_AGG   0ULL           // bf16 [2][50000][128] = 25,600,000
#define OFF_CNT   25600000ULL    // int  [100000]        =    400,000
#define OFF_EID   26000000ULL    // int  [100000][64]    = 25,600,000
#define OFF_PSTAT 51600000ULL    // f32  [256][200]      =    204,800
#define OFF_SCALE 51804800ULL
#define OFF_SHIFT 51805312ULL
#define OFF_HB    51805824ULL    // bf16 [50000][128]    = 12,800,000

// ---------------- bucket CSR build: count + place in one pass ----------------
__global__ __launch_bounds__(256) void bucket_kernel(const int* __restrict__ row,
                                                     const int* __restrict__ col,
                                                     int* __restrict__ cnt,
                                                     int* __restrict__ eid) {
    int i = blockIdx.x * blockDim.x + threadIdx.x;
    if (i < N_EDGES) {
        const int c = col[i];
        const int r = atomicAdd(&cnt[c], 1);
        if (r < CAP) eid[(size_t)c * CAP + r] = i;
        const int rw = row[i];
        const int r2 = atomicAdd(&cnt[N_NODES + rw], 1);
        if (r2 < CAP) eid[((size_t)N_NODES + rw) * CAP + r2] = i;
    }
}

// ---------------- gather-sum: one WAVE per (node, side) task, SCALAR eids -------
// R12 fix: eids are read via uniform loads + readfirstlane into SGPRs; row loads
// are global_load_dwordx2 with SGPR base + shared lane voffset. No shfl chains,
// 8 row loads per chunk genuinely outstanding with only ~16 result VGPRs.
__global__ __launch_bounds__(256) void gather_kernel(const float* __restrict__ edge_attr,
                                                     const int* __restrict__ cnt,
                                                     const int* __restrict__ eid,
                                                     __bf16* __restrict__ agg) {
    const int lane = threadIdx.x & 63;
    const int wid  = blockIdx.x * 4 + (threadIdx.x >> 6);   // one wave per task
    const int n    = __builtin_amdgcn_readfirstlane(min(cnt[wid], CAP));
    const size_t beg = (size_t)wid * CAP;
    const int c2   = lane * 2;                              // channel base (float2)
    f32x2 acc0 = (f32x2)0.0f, acc1 = (f32x2)0.0f,
          acc2 = (f32x2)0.0f, acc3 = (f32x2)0.0f;

    for (int base = 0; base < n; base += 8) {
        // 8 edge ids via uniform-address vector loads -> SGPRs
        const int4 ea = *(const int4*)(eid + beg + base);
        const int4 eb = *(const int4*)(eid + beg + base + 4);
        const int s0 = __builtin_amdgcn_readfirstlane(ea.x);
        int s1 = __builtin_amdgcn_readfirstlane(ea.y);
        int s2 = __builtin_amdgcn_readfirstlane(ea.z);
        int s3 = __builtin_amdgcn_readfirstlane(ea.w);
        int s4 = __builtin_amdgcn_readfirstlane(eb.x);
        int s5 = __builtin_amdgcn_readfirstlane(eb.y);
        int s6 = __builtin_amdgcn_readfirstlane(eb.z);
        int s7 = __builtin_amdgcn_readfirstlane(eb.w);
        // clamp tail slots to a valid edge (uniform scalar selects)
        s1 = (base + 1 < n) ? s1 : s0;
        s2 = (base + 2 < n) ? s2 : s0;
        s3 = (base + 3 < n) ? s3 : s0;
        s4 = (base + 4 < n) ? s4 : s0;
        s5 = (base + 5 < n) ? s5 : s0;
        s6 = (base + 6 < n) ? s6 : s0;
        s7 = (base + 7 < n) ? s7 : s0;
        // 8 independent row loads, SGPR base + lane voffset
        const f32x2 v0 = *(const f32x2*)(edge_attr + (size_t)s0 * D_IN + c2);
        const f32x2 v1 = *(const f32x2*)(edge_attr + (size_t)s1 * D_IN + c2);
        const f32x2 v2 = *(const f32x2*)(edge_attr + (size_t)s2 * D_IN + c2);
        const f32x2 v3 = *(const f32x2*)(edge_attr + (size_t)s3 * D_IN + c2);
        const f32x2 v4 = *(const f32x2*)(edge_attr + (size_t)s4 * D_IN + c2);
        const f32x2 v5 = *(const f32x2*)(edge_attr + (size_t)s5 * D_IN + c2);
        const f32x2 v6 = *(const f32x2*)(edge_attr + (size_t)s6 * D_IN + c2);
        const f32x2 v7 = *(const f32x2*)(edge_attr + (size_t)s7 * D_IN + c2);
        __builtin_amdgcn_sched_barrier(0);   // issue all 8 before consuming
        acc0 += v0;                          // base+0 < n always (loop cond)
        if (base + 1 < n) acc1 += v1;
        if (base + 2 < n) acc2 += v2;
        if (base + 3 < n) acc3 += v3;
        if (base + 4 < n) acc0 += v4;
        if (base + 5 < n) acc1 += v5;
        if (base + 6 < n) acc2 += v6;
        if (base + 7 < n) acc3 += v7;
    }
    acc0 += acc1;  acc2 += acc3;  acc0 += acc2;

    bf16x2 o;
    o[0] = (__bf16)acc0[0];
    o[1] = (__bf16)acc0[1];
    *(bf16x2*)(agg + (size_t)wid * D_IN + c2) = o;
}

// ---------------- fused GEMM + bias + ReLU + BN-partials ----------------
// grid (NBX, 2): blockIdx.y = channel half (64 ch). W-half staged f32->bf16 into
// LDS (XOR-swizzled). Block = 8 waves; wave w -> nodes [bx*256 + w*32, +32).
// h stored bf16; per-channel stats exit as per-block partials (f32, exact acc).
#define ROW_B 768   // bytes per W row in LDS (384 * 2)
__global__ __launch_bounds__(512) void gemm_kernel(
    const __bf16* __restrict__ agg, const float* __restrict__ node_attr,
    const float* __restrict__ W, const float* __restrict__ bias,
    __bf16* __restrict__ hb, float* __restrict__ pstat) {
    __shared__ __align__(16) char Ws[64 * ROW_B];   // 49152 B
    __shared__ float sred[2][8][64];                // +4096 B

    const int lane = threadIdx.x & 63;
    const int w    = threadIdx.x >> 6;
    const int m    = lane & 15;   // A-row / C-col lane index
    const int g    = lane >> 4;   // k-group
    const int cy   = blockIdx.y;  // channel half

    // ---- stage W-half into LDS (f32 -> bf16), swizzled: byte ^= ((row&7)<<4) ----
    {
        const float* src = W + (size_t)cy * 64 * D_K;
#pragma unroll
        for (int i = 0; i < 6; ++i) {
            const int idx = i * 512 + threadIdx.x;        // vec16 index, 3072 total
            const int r   = idx / 48;                     // 48 vec16 per row
            const int c8  = idx % 48;                     // 8-elem group in row
            const float* p = src + (size_t)r * D_K + c8 * 8;
            f32x4 v0 = *(const f32x4*)p, v1 = *(const f32x4*)(p + 4);
            bf16x8 v;
#pragma unroll
            for (int q = 0; q < 4; ++q) { v[q] = (__bf16)v0[q]; v[q + 4] = (__bf16)v1[q]; }
            *(bf16x8*)(Ws + r * ROW_B + ((c8 * 16) ^ ((r & 7) << 4))) = v;
        }
    }
    __syncthreads();

    const int nodeA0 = blockIdx.x * 256 + w * 32 + m;
    const int nodeA1 = nodeA0 + 16;

    f32x4 acc[2][4];
#pragma unroll
    for (int i = 0; i < 2; ++i)
#pragma unroll
        for (int f = 0; f < 4; ++f) acc[i][f] = (f32x4)0.0f;

#pragma unroll
    for (int ks = 0; ks < 12; ++ks) {
        const int k0 = ks * 32;
        bf16x8 a0, a1;
#pragma unroll
        for (int i = 0; i < 8; ++i) { a0[i] = (__bf16)0.0f; a1[i] = (__bf16)0.0f; }
        if (ks < 8) {   // recv/send stored bf16
            const size_t base = (size_t)(k0 >> 7) * (N_NODES * D_IN) + (k0 & 127) + g * 8;
            if (nodeA0 < N_NODES) a0 = *(const bf16x8*)(agg + base + (size_t)nodeA0 * D_IN);
            if (nodeA1 < N_NODES) a1 = *(const bf16x8*)(agg + base + (size_t)nodeA1 * D_IN);
        } else {        // node_attr f32 -> bf16
            const size_t base = (k0 - 256) + g * 8;
            if (nodeA0 < N_NODES) {
                const float* p = node_attr + (size_t)nodeA0 * D_IN + base;
                f32x4 v0 = *(const f32x4*)p, v1 = *(const f32x4*)(p + 4);
#pragma unroll
                for (int i = 0; i < 4; ++i) { a0[i] = (__bf16)v0[i]; a0[i + 4] = (__bf16)v1[i]; }
            }
            if (nodeA1 < N_NODES) {
                const float* p = node_attr + (size_t)nodeA1 * D_IN + base;
                f32x4 v0 = *(const f32x4*)p, v1 = *(const f32x4*)(p + 4);
#pragma unroll
                for (int i = 0; i < 4; ++i) { a1[i] = (__bf16)v0[i]; a1[i + 4] = (__bf16)v1[i]; }
            }
        }
#pragma unroll
        for (int f = 0; f < 4; ++f) {
            const int r = f * 16 + m;
            const int cb = (k0 + g * 8) * 2;
            bf16x8 bfrag = *(const bf16x8*)(Ws + r * ROW_B + (cb ^ ((r & 7) << 4)));
            acc[0][f] = __builtin_amdgcn_mfma_f32_16x16x32_bf16(a0, bfrag, acc[0][f], 0, 0, 0);
            acc[1][f] = __builtin_amdgcn_mfma_f32_16x16x32_bf16(a1, bfrag, acc[1][f], 0, 0, 0);
        }
    }

    // epilogue: bias + relu + write h (bf16) + per-wave channel stats into LDS
#pragma unroll
    for (int f = 0; f < 4; ++f) {
        const int j  = cy * 64 + f * 16 + m;
        const float bj = bias[j];
        float s1 = 0.0f, s2 = 0.0f;
#pragma unroll
        for (int i = 0; i < 2; ++i) {
#pragma unroll
            for (int r = 0; r < 4; ++r) {
                const int nodeC = blockIdx.x * 256 + w * 32 + i * 16 + g * 4 + r;
                float v = acc[i][f][r] + bj;
                v = v > 0.0f ? v : 0.0f;
                if (nodeC < N_NODES) {
                    hb[(size_t)nodeC * D_OUT + j] = (__bf16)v;
                    s1 += v;
                    s2 += v * v;
                }
            }
        }
        s1 += __shfl_xor(s1, 16, 64);  s2 += __shfl_xor(s2, 16, 64);
        s1 += __shfl_xor(s1, 32, 64);  s2 += __shfl_xor(s2, 32, 64);
        if (lane < 16) { sred[0][w][f * 16 + m] = s1; sred[1][w][f * 16 + m] = s2; }
    }
    __syncthreads();
    if (threadIdx.x < 128) {
        const int s = threadIdx.x >> 6;
        const int c = threadIdx.x & 63;
        float v = 0.0f;
#pragma unroll
        for (int q = 0; q < 8; ++q) v += sred[s][q][c];
        pstat[(size_t)(s * 128 + cy * 64 + c) * PSTRIDE + blockIdx.x] = v;
    }
}

// ---------------- BN finalize: reduce partials + scale/shift ----------------
__global__ __launch_bounds__(256) void bn_finalize_kernel(
    const float* __restrict__ pstat, const float* __restrict__ gamma,
    const float* __restrict__ beta, float* __restrict__ scale, float* __restrict__ shift) {
    const int j = blockIdx.x;   // channel 0..127
    float a1 = 0.0f, a2 = 0.0f;
    for (int b = threadIdx.x; b < NBX; b += 256) {
        a1 += pstat[(size_t)j * PSTRIDE + b];
        a2 += pstat[(size_t)(128 + j) * PSTRIDE + b];
    }
#pragma unroll
    for (int ofs = 32; ofs >= 1; ofs >>= 1) {
        a1 += __shfl_xor(a1, ofs, 64);
        a2 += __shfl_xor(a2, ofs, 64);
    }
    __shared__ float w1[4], w2[4];
    if ((threadIdx.x & 63) == 0) { w1[threadIdx.x >> 6] = a1; w2[threadIdx.x >> 6] = a2; }
    __syncthreads();
    if (threadIdx.x == 0) {
        const float S1 = w1[0] + w1[1] + w1[2] + w1[3];
        const float S2 = w2[0] + w2[1] + w2[2] + w2[3];
        const float inv_n = 1.0f / (float)N_NODES;
        const float mu  = S1 * inv_n;
        const float var = S2 * inv_n - mu * mu;
        const float sc  = gamma[j] * rsqrtf(var + BN_EPS);
        scale[j] = sc;
        shift[j] = beta[j] - mu * sc;
    }
}

// ---------------- BN apply: read bf16 h, write f32 out ----------------
__global__ __launch_bounds__(256) void bn_apply_kernel(
    const __bf16* __restrict__ hb, float* __restrict__ out,
    const float* __restrict__ scale, const float* __restrict__ shift) {
    size_t i = ((size_t)blockIdx.x * blockDim.x + threadIdx.x) * 8;
    if (i >= (size_t)N_NODES * D_OUT) return;
    const int j0 = (int)(i & 127);
    bf16x8 v = *(const bf16x8*)(hb + i);
    f32x4 a, b;
#pragma unroll
    for (int q = 0; q < 4; ++q) {
        a[q] = (float)v[q]     * scale[j0 + q]     + shift[j0 + q];
        b[q] = (float)v[q + 4] * scale[j0 + 4 + q] + shift[j0 + 4 + q];
    }
    *(f32x4*)(out + i)     = a;
    *(f32x4*)(out + i + 4) = b;
}

extern "C" void kernel_launch(void* const* d_in, const int* in_sizes, int n_in,
                              void* d_out, int out_size, void* d_ws, size_t ws_size,
                              hipStream_t stream) {
    const float* edge_attr = (const float*)d_in[0];
    const float* node_attr = (const float*)d_in[1];
    const float* W         = (const float*)d_in[2];
    const float* bias      = (const float*)d_in[3];
    const float* gamma     = (const float*)d_in[4];
    const float* beta      = (const float*)d_in[5];
    const int*   row       = (const int*)d_in[6];
    const int*   col       = (const int*)d_in[7];
    float* out = (float*)d_out;

    char* ws = (char*)d_ws;
    __bf16* agg   = (__bf16*)(ws + OFF_AGG);
    int*    cnt   = (int*)(ws + OFF_CNT);
    int*    eid   = (int*)(ws + OFF_EID);
    float*  pstat = (float*)(ws + OFF_PSTAT);
    float*  scale = (float*)(ws + OFF_SCALE);
    float*  shift = (float*)(ws + OFF_SHIFT);
    __bf16* hb    = (__bf16*)(ws + OFF_HB);

    hipMemsetAsync(cnt, 0, N_TASK * sizeof(int), stream);

    bucket_kernel<<<(N_EDGES + 255) / 256, 256, 0, stream>>>(row, col, cnt, eid);
    gather_kernel<<<N_TASK / 4, 256, 0, stream>>>(edge_attr, cnt, eid, agg);
    dim3 ggrid(NBX, 2);
    gemm_kernel<<<ggrid, 512, 0, stream>>>(agg, node_attr, W, bias, hb, pstat);
    bn_finalize_kernel<<<128, 256, 0, stream>>>(pstat, gamma, beta, scale, shift);
    bn_apply_kernel<<<(N_NODES * D_OUT / 8 + 255) / 256, 256, 0, stream>>>(hb, out, scale, shift);
}

// Round 13
// 217.441 us; speedup vs baseline: 1.0001x; 1.0001x over previous
//
#include <hip/hip_runtime.h>
#include <hip/hip_bf16.h>

#define N_NODES 50000
#define N_EDGES 500000
#define D_IN    128
#define D_K     384
#define D_OUT   128
#define BN_EPS  1e-5f
#define N_TASK  (2 * N_NODES)   // recv tasks then send tasks
#define CAP     64              // bucket capacity (max degree ~30 for Poisson(10))
#define NBX     ((N_NODES + 255) / 256)    // 196 gemm x-blocks (256 nodes each)
#define PSTRIDE 200                        // padded partial stride (>= NBX)

typedef __bf16 bf16x8 __attribute__((ext_vector_type(8)));
typedef __bf16 bf16x4 __attribute__((ext_vector_type(4)));
typedef __bf16 bf16x2 __attribute__((ext_vector_type(2)));
typedef float  f32x4  __attribute__((ext_vector_type(4)));
typedef float  f32x2  __attribute__((ext_vector_type(2)));

// ---- workspace layout (bytes) ----
#define OFF_AGG   0ULL           // bf16 [2][50000][128] = 25,600,000
#define OFF_CNT   25600000ULL    // int  [100000]        =    400,000
#define OFF_EID   26000000ULL    // int  [100000][64]    = 25,600,000
#define OFF_PSTAT 51600000ULL    // f32  [256][200]      =    204,800
#define OFF_SCALE 51804800ULL
#define OFF_SHIFT 51805312ULL
#define OFF_HB    51805824ULL    // bf16 [50000][128]    = 12,800,000

// async global -> LDS copy, 16B per lane (result-free: no VGPR round trip)
__device__ __forceinline__ void gload_lds16(const void* g, void* l) {
    __builtin_amdgcn_global_load_lds(
        (const __attribute__((address_space(1))) void*)g,
        (__attribute__((address_space(3))) void*)l, 16, 0, 0);
}

// ---------------- bucket CSR build: count + place in one pass ----------------
__global__ __launch_bounds__(256) void bucket_kernel(const int* __restrict__ row,
                                                     const int* __restrict__ col,
                                                     int* __restrict__ cnt,
                                                     int* __restrict__ eid) {
    int i = blockIdx.x * blockDim.x + threadIdx.x;
    if (i < N_EDGES) {
        const int c = col[i];
        const int r = atomicAdd(&cnt[c], 1);
        if (r < CAP) eid[(size_t)c * CAP + r] = i;
        const int rw = row[i];
        const int r2 = atomicAdd(&cnt[N_NODES + rw], 1);
        if (r2 < CAP) eid[((size_t)N_NODES + rw) * CAP + r2] = i;
    }
}

// ---------------- gather-sum: one WAVE per task, async LDS staging ----------------
// R13 fix: edge rows are staged via global_load_lds (NO VGPR results -> the
// register allocator cannot serialize them; up to 8 x 1KB copies outstanding
// per chunk). One vmcnt(0) per 16-edge chunk, then cheap ds_read accumulates.
__global__ __launch_bounds__(256) void gather_kernel(const float* __restrict__ edge_attr,
                                                     const int* __restrict__ cnt,
                                                     const int* __restrict__ eid,
                                                     __bf16* __restrict__ agg) {
    __shared__ __align__(16) float ebuf[4][16][D_IN];   // 8KB per wave, 32KB/block
    const int lane = threadIdx.x & 63;
    const int w    = threadIdx.x >> 6;
    const int wid  = blockIdx.x * 4 + w;                // one wave per task
    const int n    = __builtin_amdgcn_readfirstlane(min(cnt[wid], CAP));
    const size_t beg = (size_t)wid * CAP;
    const int half = lane >> 5;                         // 0: even row, 1: odd row
    const int hl   = lane & 31;
    f32x2 acc0 = (f32x2)0.0f, acc1 = (f32x2)0.0f;

    for (int cb = 0; cb < n; cb += 16) {
        const int m2 = min(n - cb, 16);
        const int kp = (m2 + 1) >> 1;                   // row-pairs to stage
        // 16 edge ids, coalesced, one load (lanes >= m2 get 0 -> valid row, unused)
        const int e_reg = (lane < m2) ? eid[beg + cb + lane] : 0;
        // issue kp async 1KB copies back-to-back (no VGPR results)
        for (int k = 0; k < kp; ++k) {
            const int e = __shfl(e_reg, 2 * k + half);  // lanes 0-31: e_{2k}, 32-63: e_{2k+1}
            gload_lds16(edge_attr + (size_t)e * D_IN + hl * 4, &ebuf[w][2 * k][0]);
        }
        asm volatile("s_waitcnt vmcnt(0)" ::: "memory");
        __builtin_amdgcn_sched_barrier(0);
        // accumulate: 2 channels per lane from each staged row (2-way bank alias = free)
#pragma unroll
        for (int r = 0; r < 16; r += 2) {
            if (r < m2)     acc0 += *(const f32x2*)&ebuf[w][r][lane * 2];
            if (r + 1 < m2) acc1 += *(const f32x2*)&ebuf[w][r + 1][lane * 2];
        }
    }
    acc0 += acc1;

    bf16x2 o;
    o[0] = (__bf16)acc0[0];
    o[1] = (__bf16)acc0[1];
    *(bf16x2*)(agg + (size_t)wid * D_IN + lane * 2) = o;
}

// ---------------- fused GEMM + bias + ReLU + BN-partials ----------------
// grid (NBX, 2): blockIdx.y = channel half (64 ch). W-half staged f32->bf16 into
// LDS (XOR-swizzled). Block = 8 waves; wave w -> nodes [bx*256 + w*32, +32).
// h stored bf16; per-channel stats exit as per-block partials (f32, exact acc).
#define ROW_B 768   // bytes per W row in LDS (384 * 2)
__global__ __launch_bounds__(512) void gemm_kernel(
    const __bf16* __restrict__ agg, const float* __restrict__ node_attr,
    const float* __restrict__ W, const float* __restrict__ bias,
    __bf16* __restrict__ hb, float* __restrict__ pstat) {
    __shared__ __align__(16) char Ws[64 * ROW_B];   // 49152 B
    __shared__ float sred[2][8][64];                // +4096 B

    const int lane = threadIdx.x & 63;
    const int w    = threadIdx.x >> 6;
    const int m    = lane & 15;   // A-row / C-col lane index
    const int g    = lane >> 4;   // k-group
    const int cy   = blockIdx.y;  // channel half

    // ---- stage W-half into LDS (f32 -> bf16), swizzled: byte ^= ((row&7)<<4) ----
    {
        const float* src = W + (size_t)cy * 64 * D_K;
#pragma unroll
        for (int i = 0; i < 6; ++i) {
            const int idx = i * 512 + threadIdx.x;        // vec16 index, 3072 total
            const int r   = idx / 48;                     // 48 vec16 per row
            const int c8  = idx % 48;                     // 8-elem group in row
            const float* p = src + (size_t)r * D_K + c8 * 8;
            f32x4 v0 = *(const f32x4*)p, v1 = *(const f32x4*)(p + 4);
            bf16x8 v;
#pragma unroll
            for (int q = 0; q < 4; ++q) { v[q] = (__bf16)v0[q]; v[q + 4] = (__bf16)v1[q]; }
            *(bf16x8*)(Ws + r * ROW_B + ((c8 * 16) ^ ((r & 7) << 4))) = v;
        }
    }
    __syncthreads();

    const int nodeA0 = blockIdx.x * 256 + w * 32 + m;
    const int nodeA1 = nodeA0 + 16;

    f32x4 acc[2][4];
#pragma unroll
    for (int i = 0; i < 2; ++i)
#pragma unroll
        for (int f = 0; f < 4; ++f) acc[i][f] = (f32x4)0.0f;

#pragma unroll
    for (int ks = 0; ks < 12; ++ks) {
        const int k0 = ks * 32;
        bf16x8 a0, a1;
#pragma unroll
        for (int i = 0; i < 8; ++i) { a0[i] = (__bf16)0.0f; a1[i] = (__bf16)0.0f; }
        if (ks < 8) {   // recv/send stored bf16
            const size_t base = (size_t)(k0 >> 7) * (N_NODES * D_IN) + (k0 & 127) + g * 8;
            if (nodeA0 < N_NODES) a0 = *(const bf16x8*)(agg + base + (size_t)nodeA0 * D_IN);
            if (nodeA1 < N_NODES) a1 = *(const bf16x8*)(agg + base + (size_t)nodeA1 * D_IN);
        } else {        // node_attr f32 -> bf16
            const size_t base = (k0 - 256) + g * 8;
            if (nodeA0 < N_NODES) {
                const float* p = node_attr + (size_t)nodeA0 * D_IN + base;
                f32x4 v0 = *(const f32x4*)p, v1 = *(const f32x4*)(p + 4);
#pragma unroll
                for (int i = 0; i < 4; ++i) { a0[i] = (__bf16)v0[i]; a0[i + 4] = (__bf16)v1[i]; }
            }
            if (nodeA1 < N_NODES) {
                const float* p = node_attr + (size_t)nodeA1 * D_IN + base;
                f32x4 v0 = *(const f32x4*)p, v1 = *(const f32x4*)(p + 4);
#pragma unroll
                for (int i = 0; i < 4; ++i) { a1[i] = (__bf16)v0[i]; a1[i + 4] = (__bf16)v1[i]; }
            }
        }
#pragma unroll
        for (int f = 0; f < 4; ++f) {
            const int r = f * 16 + m;
            const int cb = (k0 + g * 8) * 2;
            bf16x8 bfrag = *(const bf16x8*)(Ws + r * ROW_B + (cb ^ ((r & 7) << 4)));
            acc[0][f] = __builtin_amdgcn_mfma_f32_16x16x32_bf16(a0, bfrag, acc[0][f], 0, 0, 0);
            acc[1][f] = __builtin_amdgcn_mfma_f32_16x16x32_bf16(a1, bfrag, acc[1][f], 0, 0, 0);
        }
    }

    // epilogue: bias + relu + write h (bf16) + per-wave channel stats into LDS
#pragma unroll
    for (int f = 0; f < 4; ++f) {
        const int j  = cy * 64 + f * 16 + m;
        const float bj = bias[j];
        float s1 = 0.0f, s2 = 0.0f;
#pragma unroll
        for (int i = 0; i < 2; ++i) {
#pragma unroll
            for (int r = 0; r < 4; ++r) {
                const int nodeC = blockIdx.x * 256 + w * 32 + i * 16 + g * 4 + r;
                float v = acc[i][f][r] + bj;
                v = v > 0.0f ? v : 0.0f;
                if (nodeC < N_NODES) {
                    hb[(size_t)nodeC * D_OUT + j] = (__bf16)v;
                    s1 += v;
                    s2 += v * v;
                }
            }
        }
        s1 += __shfl_xor(s1, 16, 64);  s2 += __shfl_xor(s2, 16, 64);
        s1 += __shfl_xor(s1, 32, 64);  s2 += __shfl_xor(s2, 32, 64);
        if (lane < 16) { sred[0][w][f * 16 + m] = s1; sred[1][w][f * 16 + m] = s2; }
    }
    __syncthreads();
    if (threadIdx.x < 128) {
        const int s = threadIdx.x >> 6;
        const int c = threadIdx.x & 63;
        float v = 0.0f;
#pragma unroll
        for (int q = 0; q < 8; ++q) v += sred[s][q][c];
        pstat[(size_t)(s * 128 + cy * 64 + c) * PSTRIDE + blockIdx.x] = v;
    }
}

// ---------------- BN finalize: reduce partials + scale/shift ----------------
__global__ __launch_bounds__(256) void bn_finalize_kernel(
    const float* __restrict__ pstat, const float* __restrict__ gamma,
    const float* __restrict__ beta, float* __restrict__ scale, float* __restrict__ shift) {
    const int j = blockIdx.x;   // channel 0..127
    float a1 = 0.0f, a2 = 0.0f;
    for (int b = threadIdx.x; b < NBX; b += 256) {
        a1 += pstat[(size_t)j * PSTRIDE + b];
        a2 += pstat[(size_t)(128 + j) * PSTRIDE + b];
    }
#pragma unroll
    for (int ofs = 32; ofs >= 1; ofs >>= 1) {
        a1 += __shfl_xor(a1, ofs, 64);
        a2 += __shfl_xor(a2, ofs, 64);
    }
    __shared__ float w1[4], w2[4];
    if ((threadIdx.x & 63) == 0) { w1[threadIdx.x >> 6] = a1; w2[threadIdx.x >> 6] = a2; }
    __syncthreads();
    if (threadIdx.x == 0) {
        const float S1 = w1[0] + w1[1] + w1[2] + w1[3];
        const float S2 = w2[0] + w2[1] + w2[2] + w2[3];
        const float inv_n = 1.0f / (float)N_NODES;
        const float mu  = S1 * inv_n;
        const float var = S2 * inv_n - mu * mu;
        const float sc  = gamma[j] * rsqrtf(var + BN_EPS);
        scale[j] = sc;
        shift[j] = beta[j] - mu * sc;
    }
}

// ---------------- BN apply: read bf16 h, write f32 out ----------------
__global__ __launch_bounds__(256) void bn_apply_kernel(
    const __bf16* __restrict__ hb, float* __restrict__ out,
    const float* __restrict__ scale, const float* __restrict__ shift) {
    size_t i = ((size_t)blockIdx.x * blockDim.x + threadIdx.x) * 8;
    if (i >= (size_t)N_NODES * D_OUT) return;
    const int j0 = (int)(i & 127);
    bf16x8 v = *(const bf16x8*)(hb + i);
    f32x4 a, b;
#pragma unroll
    for (int q = 0; q < 4; ++q) {
        a[q] = (float)v[q]     * scale[j0 + q]     + shift[j0 + q];
        b[q] = (float)v[q + 4] * scale[j0 + 4 + q] + shift[j0 + 4 + q];
    }
    *(f32x4*)(out + i)     = a;
    *(f32x4*)(out + i + 4) = b;
}

extern "C" void kernel_launch(void* const* d_in, const int* in_sizes, int n_in,
                              void* d_out, int out_size, void* d_ws, size_t ws_size,
                              hipStream_t stream) {
    const float* edge_attr = (const float*)d_in[0];
    const float* node_attr = (const float*)d_in[1];
    const float* W         = (const float*)d_in[2];
    const float* bias      = (const float*)d_in[3];
    const float* gamma     = (const float*)d_in[4];
    const float* beta      = (const float*)d_in[5];
    const int*   row       = (const int*)d_in[6];
    const int*   col       = (const int*)d_in[7];
    float* out = (float*)d_out;

    char* ws = (char*)d_ws;
    __bf16* agg   = (__bf16*)(ws + OFF_AGG);
    int*    cnt   = (int*)(ws + OFF_CNT);
    int*    eid   = (int*)(ws + OFF_EID);
    float*  pstat = (float*)(ws + OFF_PSTAT);
    float*  scale = (float*)(ws + OFF_SCALE);
    float*  shift = (float*)(ws + OFF_SHIFT);
    __bf16* hb    = (__bf16*)(ws + OFF_HB);

    hipMemsetAsync(cnt, 0, N_TASK * sizeof(int), stream);

    bucket_kernel<<<(N_EDGES + 255) / 256, 256, 0, stream>>>(row, col, cnt, eid);
    gather_kernel<<<N_TASK / 4, 256, 0, stream>>>(edge_attr, cnt, eid, agg);
    dim3 ggrid(NBX, 2);
    gemm_kernel<<<ggrid, 512, 0, stream>>>(agg, node_attr, W, bias, hb, pstat);
    bn_finalize_kernel<<<128, 256, 0, stream>>>(pstat, gamma, beta, scale, shift);
    bn_apply_kernel<<<(N_NODES * D_OUT / 8 + 255) / 256, 256, 0, stream>>>(hb, out, scale, shift);
}